// Round 9
// baseline (167.158 us; speedup 1.0000x reference)
//
#include <hip/hip_runtime.h>
#include <math.h>

#define M_ 4
#define A_ 256
#define RBF_ 64
#define F_ 32
#define H_ 32
#define SI_ 32
#define TF_ 128   // 4 tags * F

typedef __attribute__((ext_vector_type(8))) short bf16x8;
typedef __attribute__((ext_vector_type(4))) float f32x4;
typedef __attribute__((ext_vector_type(3))) float f32x3;

__device__ __forceinline__ unsigned short f2bf(float f) {
  union { float f; unsigned u; } v; v.f = f;
  unsigned r = v.u + 0x7FFFu + ((v.u >> 16) & 1u);   // RNE bf16 (weights, one-time)
  return (unsigned short)(r >> 16);
}

// pack two fp32 -> two bf16 (round-half-up: +0x8000 then take hi16) in 3 VALU
__device__ __forceinline__ unsigned pack2bf(float lo, float hi) {
  union { float f; unsigned u; } a, b; a.f = lo; b.f = hi;
  return __builtin_amdgcn_perm(b.u + 0x8000u, a.u + 0x8000u, 0x07060302u);
}

__device__ __forceinline__ float sspf(float x) {
  // log(0.5*exp(x)+0.5) = softplus(x) - ln2, numerically stable
  return fmaxf(x, 0.f) + log1pf(expf(-fabsf(x))) - 0.6931471805599453f;
}

// ---------------------------------------------------------------------------
// Setup: collapse the two linear Dense layers per tag into one 64x32 map.
// ws layout: WcT bf16 [tf=128][k=64] (16384 B) | bc fp32[128] at +16384.
// tf = tag*32 + f, tag order {00,01,10,11}.
// ---------------------------------------------------------------------------
__global__ __launch_bounds__(256) void combine_weights(
    const float* __restrict__ w1_00, const float* __restrict__ b1_00,
    const float* __restrict__ w2_00, const float* __restrict__ b2_00,
    const float* __restrict__ w1_01, const float* __restrict__ b1_01,
    const float* __restrict__ w2_01, const float* __restrict__ b2_01,
    const float* __restrict__ w1_10, const float* __restrict__ b1_10,
    const float* __restrict__ w2_10, const float* __restrict__ b2_10,
    const float* __restrict__ w1_11, const float* __restrict__ b1_11,
    const float* __restrict__ w2_11, const float* __restrict__ b2_11,
    unsigned short* __restrict__ wsT, float* __restrict__ bcw)
{
  const float* w1s[4] = {w1_00, w1_01, w1_10, w1_11};
  const float* b1s[4] = {b1_00, b1_01, b1_10, b1_11};
  const float* w2s[4] = {w2_00, w2_01, w2_10, w2_11};
  const float* b2s[4] = {b2_00, b2_01, b2_10, b2_11};
  int tid = blockIdx.x * 256 + threadIdx.x;    // 0..8191
  int k   = tid >> 7;
  int tf  = tid & 127;
  int tag = tf >> 5, f = tf & 31;
  const float* w1 = w1s[tag];
  const float* w2 = w2s[tag];
  float s = 0.f;
  for (int h = 0; h < H_; ++h) s += w1[k * H_ + h] * w2[h * F_ + f];
  wsT[tf * 64 + k] = f2bf(s);                  // transposed for B-frag loads
  if (tid < TF_) {
    const float* b1 = b1s[tag];
    const float* b2 = b2s[tag];
    float sb = b2[f];
    for (int h = 0; h < H_; ++h) sb += b1[h] * w2[h * F_ + f];
    bcw[tf] = sb;                              // bias stays fp32
  }
}

// ---------------------------------------------------------------------------
// Fused conv kernel: one block per (m,a) -- grid 1024, 512 thr, 8 waves,
// single dispatch round (4 blocks/CU x 256 CU = 1024).
//  WAVE-PER-TAG (R8): wave wu (readfirstlane -> SGPR uniform branches) owns
//  ONE ct = tag*2+which tf-tile over all 16 b-tiles.
//  Operands (feat0 / feat1) double-buffered one b-tile ahead in a SHARED
//  gx/gy/gz[2][4] buffer (tag<=1 uses gx only) = 24 VGPR -> total ~60,
//  no spill at the 128 cap. DO NOT set min-waves=8 (R6: hard 64 cap -> 1.3 GB
//  scratch). vectors staged to LDS.
//  GEMM via mfma_f32_16x16x32_bf16; C-frag row(b)=quad*4+reg, col=lane&15.
//  Quad-copy reduce via shfl_xor; cat[352] in LDS (aliases consumed sA);
//  SI + activation epilogue fused on wave 0.
// LDS: sA [256][72] bf16 (36864) + sV [768] f32 (3072) = 39936 B -> 4 blk/CU.
// ---------------------------------------------------------------------------
__global__ __launch_bounds__(512, 4) void conv_main(
    const float* __restrict__ image, const float* __restrict__ vectors,
    const float* __restrict__ feat0, const float* __restrict__ feat1,
    const unsigned short* __restrict__ wsT, const float* __restrict__ bcw,
    const float* __restrict__ w_si0, const float* __restrict__ w_si1,
    const float* __restrict__ b_act0, const float* __restrict__ b_act1,
    float* __restrict__ out)
{
  __shared__ __align__(16) char smem[39936];
  unsigned short* sA  = (unsigned short*)smem;      // [256][72] bf16 = 36864 B
  float*          sV  = (float*)(smem + 36864);     // [768] f32 = 3072 B
  float*          cat = (float*)smem;               // [352] alias (post-barrier)

  const int t    = threadIdx.x;
  const int ma   = blockIdx.x;      // m*256 + a
  const int m    = ma >> 8;
  const int l    = t & 63;
  const int n    = l & 15;
  const int quad = l >> 4;
  // wave id as SGPR -> uniform branches
  const int wu    = __builtin_amdgcn_readfirstlane(t >> 6);   // 0..7
  const int which = wu & 1;
  const int tag   = wu >> 1;        // 0:'00' 1:'01' 2:'10' 3:'11'
  const int ct    = tag * 2 + which;
  const int f     = which * 16 + n; // feature column this lane owns

  // ---- Wc fragment + bias into registers (global, L2-resident) ----
  const unsigned short* wr = wsT + (ct * 16 + n) * 64 + quad * 8;
  const bf16x8 w0 = *(const bf16x8*)(wr);
  const bf16x8 w1 = *(const bf16x8*)(wr + 32);
  const float  bc = bcw[ct * 16 + n];

  // ---- stage image rows (256 b x 64 rbf) to LDS as bf16 ----
  const float* imgMA = image + (size_t)ma * A_ * RBF_;
  #pragma unroll
  for (int i = 0; i < 4; ++i) {
    int g = t + 512 * i;            // 0..2047 groups of 8 elems
    int r = g >> 3, c8 = g & 7;
    const float* src = imgMA + r * RBF_ + c8 * 8;
    float4 v0 = *(const float4*)(src);
    float4 v1 = *(const float4*)(src + 4);
    uint4 pk;
    pk.x = pack2bf(v0.x, v0.y);
    pk.y = pack2bf(v0.z, v0.w);
    pk.z = pack2bf(v1.x, v1.y);
    pk.w = pack2bf(v1.z, v1.w);
    *(uint4*)&sA[r * 72 + c8 * 8] = pk;
  }
  // ---- stage vectors (256 b x 3) to LDS ----
  #pragma unroll
  for (int i = 0; i < 2; ++i) {
    int s = t + 512 * i;
    if (s < 768) sV[s] = vectors[(size_t)ma * (A_ * 3) + s];
  }

  // lane-private feat pointers
  const float* p0 = feat0 + (size_t)(m * A_) * F_ + f;          // + b*F_
  const float* p1 = feat1 + ((size_t)(m * A_) * F_ + f) * 3;    // + b*96

  // double-buffered operands; tag<=1 uses gx only (as feat0)
  float gx[2][4], gy[2][4], gz[2][4];
  float pA = 0.f, pB0 = 0.f, pB1 = 0.f, pB2 = 0.f;

#define PF(BUF, BT) { \
    const int b0 = (BT) * 16 + quad * 4; \
    if (tag <= 1) { \
      _Pragma("unroll") \
      for (int r = 0; r < 4; ++r) gx[BUF][r] = p0[(b0 + r) * F_]; \
    } else { \
      _Pragma("unroll") \
      for (int r = 0; r < 4; ++r) { \
        f32x3 v = *(const f32x3*)&p1[(size_t)(b0 + r) * (F_ * 3)]; \
        gx[BUF][r] = v[0]; gy[BUF][r] = v[1]; gz[BUF][r] = v[2]; \
      } \
    } }

#define BODY(BT, BUF) { \
    const int brow = (BT) * 16; \
    const int lb   = brow + quad * 4; \
    const bf16x8 a0 = *(const bf16x8*)&sA[(brow + n) * 72 + quad * 8]; \
    const bf16x8 a1 = *(const bf16x8*)&sA[(brow + n) * 72 + 32 + quad * 8]; \
    f32x4 acc = {bc, bc, bc, bc}; \
    acc = __builtin_amdgcn_mfma_f32_16x16x32_bf16(a0, w0, acc, 0, 0, 0); \
    acc = __builtin_amdgcn_mfma_f32_16x16x32_bf16(a1, w1, acc, 0, 0, 0); \
    if (tag == 0) {            /* out_0x0_0 */ \
      _Pragma("unroll") \
      for (int r = 0; r < 4; ++r) pA += acc[r] * gx[BUF][r]; \
    } else if (tag == 1) {     /* out_0x1_1 = v * (R*feat0) */ \
      _Pragma("unroll") \
      for (int r = 0; r < 4; ++r) { \
        const float s  = acc[r] * gx[BUF][r]; \
        pB0 += sV[(lb + r) * 3 + 0] * s; \
        pB1 += sV[(lb + r) * 3 + 1] * s; \
        pB2 += sV[(lb + r) * 3 + 2] * s; \
      } \
    } else if (tag == 2) {     /* out_1x0_1 = R * feat1 */ \
      _Pragma("unroll") \
      for (int r = 0; r < 4; ++r) { \
        const float Rr = acc[r]; \
        pB0 += Rr * gx[BUF][r]; pB1 += Rr * gy[BUF][r]; pB2 += Rr * gz[BUF][r]; \
      } \
    } else {                   /* out_1x1_0 (dot) + out_1x1_1 (cross) */ \
      _Pragma("unroll") \
      for (int r = 0; r < 4; ++r) { \
        const float Rr = acc[r]; \
        const float ax = gx[BUF][r], ay = gy[BUF][r], az = gz[BUF][r]; \
        const float vx = sV[(lb + r) * 3 + 0]; \
        const float vy = sV[(lb + r) * 3 + 1]; \
        const float vz = sV[(lb + r) * 3 + 2]; \
        pA  += Rr * (vx * ax + vy * ay + vz * az); \
        pB0 += Rr * (vy * az - vz * ay); \
        pB1 += Rr * (vz * ax - vx * az); \
        pB2 += Rr * (vx * ay - vy * ax); \
      } \
    } }

  PF(0, 0)
  __syncthreads();

  #pragma unroll 1
  for (int bth = 0; bth < 8; ++bth) {
    const int bt0 = bth * 2;
    PF(1, bt0 + 1)        // issue next-tile loads before consuming current
    BODY(bt0, 0)
    if (bth < 7) PF(0, bt0 + 2)
    BODY(bt0 + 1, 1)
  }

  // ---- reduce the 4 quad-copies via cross-lane butterfly ----
#define QRED(x) { x += __shfl_xor(x, 16); x += __shfl_xor(x, 32); }
  QRED(pA) QRED(pB0) QRED(pB1) QRED(pB2)

  __syncthreads();   // all sA/sV reads done -> cat alias safe
  if (quad == 0) {
    // slots (cat order): out000: f | out110: 32+f | out011: 64+f*3+d
    //                    out101: 160+f*3+d | out111: 256+f*3+d
    if (tag == 0) {
      cat[f] = pA;
    } else if (tag == 1) {
      cat[64 + f * 3 + 0] = pB0;
      cat[64 + f * 3 + 1] = pB1;
      cat[64 + f * 3 + 2] = pB2;
    } else if (tag == 2) {
      cat[160 + f * 3 + 0] = pB0;
      cat[160 + f * 3 + 1] = pB1;
      cat[160 + f * 3 + 2] = pB2;
    } else {
      cat[32 + f] = pA;
      cat[256 + f * 3 + 0] = pB0;
      cat[256 + f * 3 + 1] = pB1;
      cat[256 + f * 3 + 2] = pB2;
    }
  }
  __syncthreads();

  // ---- self-interaction + equivariant activation epilogue (wave 0) ----
  const int outBase = ma * SI_;
  if (t < 32) {
    const float* wsr = w_si0 + t * 64;
    float s = 0.f;
    #pragma unroll 8
    for (int ff = 0; ff < 64; ++ff) s += cat[ff] * wsr[ff];
    s += b_act0[t];
    out[outBase + t] = sspf(s);
  } else if (t < 64) {
    int g = t - 32;
    const float* wsr = w_si1 + g * 96;
    float s0 = 0.f, s1 = 0.f, s2 = 0.f;
    #pragma unroll 8
    for (int ff = 0; ff < 96; ++ff) {
      float wv = wsr[ff];
      s0 += cat[64 + ff * 3 + 0] * wv;
      s1 += cat[64 + ff * 3 + 1] * wv;
      s2 += cat[64 + ff * 3 + 2] * wv;
    }
    float n2 = s0 * s0 + s1 * s1 + s2 * s2;
    float n1 = sqrtf(fmaxf(n2, 1e-7f));     // norm_with_epsilon, EPS=1e-7
    float a1 = sspf(n1 + b_act1[g]);
    float sc = a1 / n1;
    int ob = M_ * A_ * SI_ + (outBase + g) * 3;   // o0 is 32768 floats
    out[ob + 0] = s0 * sc;
    out[ob + 1] = s1 * sc;
    out[ob + 2] = s2 * sc;
  }
}

extern "C" void kernel_launch(void* const* d_in, const int* in_sizes, int n_in,
                              void* d_out, int out_size, void* d_ws, size_t ws_size,
                              hipStream_t stream) {
  const float* image   = (const float*)d_in[0];
  const float* vectors = (const float*)d_in[1];
  const float* feat0   = (const float*)d_in[2];
  const float* feat1   = (const float*)d_in[3];
  const float* w_si0   = (const float*)d_in[20];
  const float* w_si1   = (const float*)d_in[21];
  const float* b_act0  = (const float*)d_in[22];
  const float* b_act1  = (const float*)d_in[23];
  unsigned short* wsT = (unsigned short*)d_ws;           // 128*64 bf16 = 16384 B
  float* bcw  = (float*)((char*)d_ws + 16384);           // 128 f32
  float* out  = (float*)d_out;

  combine_weights<<<32, 256, 0, stream>>>(
      (const float*)d_in[4],  (const float*)d_in[5],
      (const float*)d_in[6],  (const float*)d_in[7],
      (const float*)d_in[8],  (const float*)d_in[9],
      (const float*)d_in[10], (const float*)d_in[11],
      (const float*)d_in[12], (const float*)d_in[13],
      (const float*)d_in[14], (const float*)d_in[15],
      (const float*)d_in[16], (const float*)d_in[17],
      (const float*)d_in[18], (const float*)d_in[19],
      wsT, bcw);

  conv_main<<<M_ * A_, 512, 0, stream>>>(
      image, vectors, feat0, feat1, wsT, bcw,
      w_si0, w_si1, b_act0, b_act1, out);
}